// Round 2
// baseline (769.967 us; speedup 1.0000x reference)
//
#include <hip/hip_runtime.h>
#include <hip/hip_bf16.h>

typedef __bf16 bf16_t;
typedef __attribute__((ext_vector_type(8))) __bf16 bf16x8;
typedef __attribute__((ext_vector_type(4))) float f32x4;

__device__ __forceinline__ void async_copy16(void* lds, const void* g) {
  __builtin_amdgcn_global_load_lds((__attribute__((address_space(1))) void*)g,
                                   (__attribute__((address_space(3))) void*)lds,
                                   16, 0, 0);
}

// ---------------- prep kernels (tiny) ----------------
__global__ void prep_wvp(const float* __restrict__ Wv, const float* __restrict__ Wp,
                         const float* __restrict__ bp, const float* __restrict__ bv,
                         float* __restrict__ Wvp, float* __restrict__ bvp) {
  const int i = blockIdx.x;
  const int j = threadIdx.x;
  float a = 0.f;
  for (int d = 0; d < 512; ++d) a += Wv[i * 512 + d] * Wp[d * 256 + j];
  Wvp[i * 256 + j] = a;
  if (j == 0) {
    float b = 0.f;
    for (int d = 0; d < 512; ++d) b += Wv[i * 512 + d] * bp[d];
    bvp[i] = b + bv[i];
  }
}

__global__ void prep_wc(const float* __restrict__ Wo, const float* __restrict__ bo,
                        const float* __restrict__ Wvp, const float* __restrict__ bvp,
                        bf16_t* __restrict__ Wc, float* __restrict__ bcomb) {
  const int o = blockIdx.x;
  const int j = threadIdx.x;
  float a = 0.f;
  for (int i = 0; i < 512; ++i) a += Wo[o * 512 + i] * Wvp[i * 256 + j];
  Wc[o * 256 + j] = (bf16_t)a;
  if (j == 0) {
    float b = 0.f;
    for (int i = 0; i < 512; ++i) b += Wo[o * 512 + i] * bvp[i];
    bcomb[o] = b + bo[o];
  }
}

__global__ void prep_cast(const float* __restrict__ W1, const float* __restrict__ W2,
                          bf16_t* __restrict__ W1b, bf16_t* __restrict__ W2b) {
  const int idx = (blockIdx.x * 256 + threadIdx.x) * 8;
  const float* s;
  bf16_t* d;
  if (idx < 524288) { s = W1 + idx; d = W1b + idx; }
  else { s = W2 + (idx - 524288); d = W2b + (idx - 524288); }
  float4 u0 = *(const float4*)s;
  float4 u1 = *(const float4*)(s + 4);
  bf16x8 v;
  v[0] = (bf16_t)u0.x; v[1] = (bf16_t)u0.y; v[2] = (bf16_t)u0.z; v[3] = (bf16_t)u0.w;
  v[4] = (bf16_t)u1.x; v[5] = (bf16_t)u1.y; v[6] = (bf16_t)u1.z; v[7] = (bf16_t)u1.w;
  *(bf16x8*)d = v;
}

// ---------------- G1: 64x512 tile, K=256, LN1 fused ----------------
// A = pert fp32 [65536][256] (converted on stage), B = Wc bf16 [512][256] (async LDS)
// out x bf16 [65536][512], coalesced via LDS transpose.
__global__ __launch_bounds__(256) void gemm_ln1(
    const float* __restrict__ Apf, const bf16_t* __restrict__ Bw,
    const float* __restrict__ bias, const float* __restrict__ cellRes,
    const float* __restrict__ gamma, const float* __restrict__ beta,
    bf16_t* __restrict__ outX) {
  __shared__ __align__(16) char smem[36864];   // lA 4KB @0, lB 32KB @4096; obuf overlays
  __shared__ float rs[4][64], rss[4][64];
  bf16_t (*lA)[32] = (bf16_t (*)[32])smem;
  bf16_t (*lB)[32] = (bf16_t (*)[32])(smem + 4096);

  const int t = threadIdx.x;
  const int lane = t & 63, w = t >> 6, r = lane & 15, q = lane >> 4;
  const int m0 = blockIdx.x * 64;

  f32x4 acc[4][8];
#pragma unroll
  for (int i = 0; i < 4; ++i)
#pragma unroll
    for (int j = 0; j < 8; ++j)
#pragma unroll
      for (int p = 0; p < 4; ++p) acc[i][j][p] = 0.f;

  const int arow = t >> 2, akc = (t & 3) * 8;

  for (int k0 = 0; k0 < 256; k0 += 32) {
    // B tile 512x32 async: 8 chunks of 16B per thread, wave-contiguous LDS dests
#pragma unroll
    for (int jj = 0; jj < 8; ++jj) {
      const int c = t + 256 * jj;
      async_copy16(smem + 4096 + c * 16,
                   Bw + (size_t)(c >> 2) * 256 + k0 + (c & 3) * 8);
    }
    // A tile 64x32: fp32 load + convert
    {
      const float* src = Apf + (size_t)(m0 + arow) * 256 + k0 + akc;
      float4 u0 = *(const float4*)src;
      float4 u1 = *(const float4*)(src + 4);
      bf16x8 v;
      v[0] = (bf16_t)u0.x; v[1] = (bf16_t)u0.y; v[2] = (bf16_t)u0.z; v[3] = (bf16_t)u0.w;
      v[4] = (bf16_t)u1.x; v[5] = (bf16_t)u1.y; v[6] = (bf16_t)u1.z; v[7] = (bf16_t)u1.w;
      *(bf16x8*)&lA[arow][akc] = v;
    }
    __syncthreads();
    bf16x8 af[4];
#pragma unroll
    for (int i = 0; i < 4; ++i) af[i] = *(const bf16x8*)&lA[16 * i + r][q * 8];
#pragma unroll
    for (int j = 0; j < 8; ++j) {
      bf16x8 bfv = *(const bf16x8*)&lB[128 * w + 16 * j + r][q * 8];
#pragma unroll
      for (int i = 0; i < 4; ++i)
        acc[i][j] = __builtin_amdgcn_mfma_f32_16x16x32_bf16(af[i], bfv, acc[i][j], 0, 0, 0);
    }
    __syncthreads();
  }

  // ---- epilogue: bias + cell residual + LN1 ----
  float bb[8], ga[8], be[8];
#pragma unroll
  for (int j = 0; j < 8; ++j) {
    const int col = 128 * w + 16 * j + r;
    bb[j] = bias[col]; ga[j] = gamma[col]; be[j] = beta[col];
  }
  float s_[4][4], ss_[4][4];
#pragma unroll
  for (int i = 0; i < 4; ++i)
#pragma unroll
    for (int p = 0; p < 4; ++p) { s_[i][p] = 0.f; ss_[i][p] = 0.f; }
#pragma unroll
  for (int j = 0; j < 8; ++j) {
    const int col = 128 * w + 16 * j + r;
#pragma unroll
    for (int i = 0; i < 4; ++i)
#pragma unroll
      for (int p = 0; p < 4; ++p) {
        const int rowg = m0 + 16 * i + 4 * q + p;
        float v = acc[i][j][p] + bb[j] + cellRes[(size_t)rowg * 512 + col];
        acc[i][j][p] = v;
        s_[i][p] += v;
        ss_[i][p] += v * v;
      }
  }
#pragma unroll
  for (int m = 1; m <= 8; m <<= 1) {
#pragma unroll
    for (int i = 0; i < 4; ++i)
#pragma unroll
      for (int p = 0; p < 4; ++p) {
        s_[i][p] += __shfl_xor(s_[i][p], m);
        ss_[i][p] += __shfl_xor(ss_[i][p], m);
      }
  }
  if (r == 0) {
#pragma unroll
    for (int i = 0; i < 4; ++i)
#pragma unroll
      for (int p = 0; p < 4; ++p) {
        rs[w][16 * i + 4 * q + p] = s_[i][p];
        rss[w][16 * i + 4 * q + p] = ss_[i][p];
      }
  }
  __syncthreads();
  float mu[4][4], inv[4][4];
#pragma unroll
  for (int i = 0; i < 4; ++i)
#pragma unroll
    for (int p = 0; p < 4; ++p) {
      const int rl = 16 * i + 4 * q + p;
      float tS = rs[0][rl] + rs[1][rl] + rs[2][rl] + rs[3][rl];
      float tQ = rss[0][rl] + rss[1][rl] + rss[2][rl] + rss[3][rl];
      float m_ = tS * (1.0f / 512.0f);
      float v_ = tQ * (1.0f / 512.0f) - m_ * m_;
      mu[i][p] = m_;
      inv[i][p] = rsqrtf(v_ + 1e-5f);
    }
  // ---- coalesced store via LDS transpose, 2 phases of 32 rows ----
  bf16_t (*obuf)[520] = (bf16_t (*)[520])smem;  // 32*520*2 = 33280 <= 36864, row=1040B (16B mult)
#pragma unroll
  for (int ph = 0; ph < 2; ++ph) {
#pragma unroll
    for (int i2 = 0; i2 < 2; ++i2) {
      const int i = ph * 2 + i2;
#pragma unroll
      for (int j = 0; j < 8; ++j)
#pragma unroll
        for (int p = 0; p < 4; ++p) {
          float v = (acc[i][j][p] - mu[i][p]) * inv[i][p] * ga[j] + be[j];
          obuf[16 * i2 + 4 * q + p][128 * w + 16 * j + r] = (bf16_t)v;
        }
    }
    __syncthreads();
    const int row = t >> 3, ch = t & 7;
#pragma unroll
    for (int cc = 0; cc < 8; ++cc) {
      bf16x8 v = *(const bf16x8*)&obuf[row][cc * 64 + ch * 8];
      *(bf16x8*)(outX + (size_t)(m0 + ph * 32 + row) * 512 + cc * 64 + ch * 8) = v;
    }
    __syncthreads();
  }
}

// ---------------- G2/G3: m97-style 128x128 tile ----------------
// EPI 1: +bias, exact GELU -> bf16 out (ldo), coalesced via LDS transpose
// EPI 2: +bias + bf16 residual -> fp32 out (ldo)
template <int K, int EPI>
__global__ __launch_bounds__(256) void gemm128(
    const bf16_t* __restrict__ A, const bf16_t* __restrict__ Bw,
    const float* __restrict__ bias, const bf16_t* __restrict__ xRes,
    bf16_t* __restrict__ outBf, float* __restrict__ outF32, const int ldo) {
  __shared__ __align__(16) char smem[17408];  // lA 8KB @0, lB 8KB @8192; obuf overlays
  bf16_t (*lA)[32] = (bf16_t (*)[32])smem;
  bf16_t (*lB)[32] = (bf16_t (*)[32])(smem + 8192);

  const int t = threadIdx.x;
  const int lane = t & 63, w = t >> 6, r = lane & 15, q = lane >> 4;
  const int m0 = blockIdx.x * 128, n0 = blockIdx.y * 128;
  const int rb = (w >> 1) * 64, cb = (w & 1) * 64;

  f32x4 acc[4][4];
#pragma unroll
  for (int i = 0; i < 4; ++i)
#pragma unroll
    for (int j = 0; j < 4; ++j)
#pragma unroll
      for (int p = 0; p < 4; ++p) acc[i][j][p] = 0.f;

  for (int k0 = 0; k0 < K; k0 += 32) {
#pragma unroll
    for (int jj = 0; jj < 2; ++jj) {
      const int c = t + 256 * jj;
      const int row = c >> 2, kc = (c & 3) * 8;
      async_copy16(smem + c * 16, A + (size_t)(m0 + row) * K + k0 + kc);
      async_copy16(smem + 8192 + c * 16, Bw + (size_t)(n0 + row) * K + k0 + kc);
    }
    __syncthreads();
    bf16x8 af[4], bfr[4];
#pragma unroll
    for (int i = 0; i < 4; ++i) af[i] = *(const bf16x8*)&lA[rb + 16 * i + r][q * 8];
#pragma unroll
    for (int j = 0; j < 4; ++j) bfr[j] = *(const bf16x8*)&lB[cb + 16 * j + r][q * 8];
#pragma unroll
    for (int i = 0; i < 4; ++i)
#pragma unroll
      for (int j = 0; j < 4; ++j)
        acc[i][j] = __builtin_amdgcn_mfma_f32_16x16x32_bf16(af[i], bfr[j], acc[i][j], 0, 0, 0);
    __syncthreads();
  }

  float bb[4];
#pragma unroll
  for (int j = 0; j < 4; ++j) bb[j] = bias[n0 + cb + 16 * j + r];

  if constexpr (EPI == 1) {
    bf16_t (*obuf)[136] = (bf16_t (*)[136])smem;  // 64*136*2 = 17408, row=272B (16B mult)
#pragma unroll
    for (int ph = 0; ph < 2; ++ph) {
      if ((w >> 1) == ph) {
#pragma unroll
        for (int i = 0; i < 4; ++i)
#pragma unroll
          for (int j = 0; j < 4; ++j)
#pragma unroll
            for (int p = 0; p < 4; ++p) {
              float v = acc[i][j][p] + bb[j];
              float g = 0.5f * v * (1.0f + erff(v * 0.70710678118654752f));
              obuf[16 * i + 4 * q + p][cb + 16 * j + r] = (bf16_t)g;
            }
      }
      __syncthreads();
      const int row = t >> 2, ch = t & 3;
#pragma unroll
      for (int cc = 0; cc < 4; ++cc) {
        bf16x8 v = *(const bf16x8*)&obuf[row][cc * 32 + ch * 8];
        *(bf16x8*)(outBf + (size_t)(m0 + ph * 64 + row) * ldo + n0 + cc * 32 + ch * 8) = v;
      }
      __syncthreads();
    }
  } else {
#pragma unroll
    for (int i = 0; i < 4; ++i)
#pragma unroll
      for (int j = 0; j < 4; ++j)
#pragma unroll
        for (int p = 0; p < 4; ++p) {
          const int rowg = m0 + rb + 16 * i + 4 * q + p;
          const int col = n0 + cb + 16 * j + r;
          float v = acc[i][j][p] + bb[j] + (float)xRes[(size_t)rowg * 512 + col];
          outF32[(size_t)rowg * ldo + col] = v;
        }
  }
}

// ---------------- LN2: in-place row layernorm on d_out ----------------
__global__ __launch_bounds__(256) void ln2_kernel(float* __restrict__ y,
                                                  const float* __restrict__ g2,
                                                  const float* __restrict__ be2) {
  const int w = threadIdx.x >> 6, lane = threadIdx.x & 63;
  const size_t row = (size_t)blockIdx.x * 4 + w;
  float* p = y + row * 512 + lane * 8;
  float4 a = *(float4*)p;
  float4 b = *(float4*)(p + 4);
  float s = a.x + a.y + a.z + a.w + b.x + b.y + b.z + b.w;
  float ss = a.x * a.x + a.y * a.y + a.z * a.z + a.w * a.w +
             b.x * b.x + b.y * b.y + b.z * b.z + b.w * b.w;
#pragma unroll
  for (int m = 1; m <= 32; m <<= 1) {
    s += __shfl_xor(s, m);
    ss += __shfl_xor(ss, m);
  }
  const float mu = s * (1.0f / 512.0f);
  const float inv = rsqrtf(ss * (1.0f / 512.0f) - mu * mu + 1e-5f);
  const float4 ga0 = *(const float4*)(g2 + lane * 8);
  const float4 ga1 = *(const float4*)(g2 + lane * 8 + 4);
  const float4 be0 = *(const float4*)(be2 + lane * 8);
  const float4 be1 = *(const float4*)(be2 + lane * 8 + 4);
  a.x = (a.x - mu) * inv * ga0.x + be0.x;
  a.y = (a.y - mu) * inv * ga0.y + be0.y;
  a.z = (a.z - mu) * inv * ga0.z + be0.z;
  a.w = (a.w - mu) * inv * ga0.w + be0.w;
  b.x = (b.x - mu) * inv * ga1.x + be1.x;
  b.y = (b.y - mu) * inv * ga1.y + be1.y;
  b.z = (b.z - mu) * inv * ga1.z + be1.z;
  b.w = (b.w - mu) * inv * ga1.w + be1.w;
  *(float4*)p = a;
  *(float4*)(p + 4) = b;
}

extern "C" void kernel_launch(void* const* d_in, const int* in_sizes, int n_in,
                              void* d_out, int out_size, void* d_ws, size_t ws_size,
                              hipStream_t stream) {
  const float* cell = (const float*)d_in[0];
  const float* pert = (const float*)d_in[1];
  const float* Wp   = (const float*)d_in[2];
  const float* bp   = (const float*)d_in[3];
  // d_in[4..7] = Wq,bq,Wk,bk: dead (softmax over a single key == 1 -> attn = v)
  const float* Wv   = (const float*)d_in[8];
  const float* bv   = (const float*)d_in[9];
  const float* Wo   = (const float*)d_in[10];
  const float* bo   = (const float*)d_in[11];
  const float* g1   = (const float*)d_in[12];
  const float* be1  = (const float*)d_in[13];
  const float* g2   = (const float*)d_in[14];
  const float* be2  = (const float*)d_in[15];
  const float* W1   = (const float*)d_in[16];
  const float* b1   = (const float*)d_in[17];
  const float* W2   = (const float*)d_in[18];
  const float* b2   = (const float*)d_in[19];

  char* ws = (char*)d_ws;
  float*  Wvp   = (float*)(ws + 0);          // 512*256*4   = 524288 (prep only)
  float*  bvp   = (float*)(ws + 524288);     // 2048
  float*  bcomb = (float*)(ws + 526336);     // 2048
  bf16_t* Wc    = (bf16_t*)(ws + 528384);    // 262144
  bf16_t* W1b   = (bf16_t*)(ws + 790528);    // 1048576
  bf16_t* W2b   = (bf16_t*)(ws + 1839104);   // 1048576
  bf16_t* xws   = (bf16_t*)(ws + 2887680);   // 65536*512*2 = 67108864
  bf16_t* hws   = (bf16_t*)(ws + 69996544);  // 65536*1024*2 = 134217728
  (void)in_sizes; (void)n_in; (void)out_size; (void)ws_size;

  prep_wvp<<<512, 256, 0, stream>>>(Wv, Wp, bp, bv, Wvp, bvp);
  prep_wc<<<512, 256, 0, stream>>>(Wo, bo, Wvp, bvp, Wc, bcomb);
  prep_cast<<<512, 256, 0, stream>>>(W1, W2, W1b, W2b);

  // G1: x = LN1(cell + pert @ Wc.T + bcomb) -> bf16
  gemm_ln1<<<1024, 256, 0, stream>>>(pert, Wc, bcomb, cell, g1, be1, xws);
  // G2: h = gelu(x @ W1.T + b1) -> bf16
  gemm128<512, 1><<<dim3(512, 8), 256, 0, stream>>>(
      xws, W1b, b1, nullptr, hws, nullptr, 1024);
  // G3: y = x + h @ W2.T + b2 -> fp32 (into d_out)
  gemm128<1024, 2><<<dim3(512, 4), 256, 0, stream>>>(
      hws, W2b, b2, xws, nullptr, (float*)d_out, 512);
  // LN2 in-place on d_out
  ln2_kernel<<<16384, 256, 0, stream>>>((float*)d_out, g2, be2);
}

// Round 3
// 764.072 us; speedup vs baseline: 1.0077x; 1.0077x over previous
//
#include <hip/hip_runtime.h>
#include <hip/hip_bf16.h>

typedef __bf16 bf16_t;
typedef __attribute__((ext_vector_type(8))) __bf16 bf16x8;
typedef __attribute__((ext_vector_type(4))) float f32x4;

__device__ __forceinline__ void async_copy16(void* lds, const void* g) {
  __builtin_amdgcn_global_load_lds((__attribute__((address_space(1))) void*)g,
                                   (__attribute__((address_space(3))) void*)lds,
                                   16, 0, 0);
}

// ---------------- prep kernels (tiny) ----------------
__global__ void prep_wvp(const float* __restrict__ Wv, const float* __restrict__ Wp,
                         const float* __restrict__ bp, const float* __restrict__ bv,
                         float* __restrict__ Wvp, float* __restrict__ bvp) {
  const int i = blockIdx.x;
  const int j = threadIdx.x;
  float a = 0.f;
#pragma unroll 8
  for (int d = 0; d < 512; ++d) a += Wv[i * 512 + d] * Wp[d * 256 + j];
  Wvp[i * 256 + j] = a;
  if (j == 0) {
    float b = 0.f;
    for (int d = 0; d < 512; ++d) b += Wv[i * 512 + d] * bp[d];
    bvp[i] = b + bv[i];
  }
}

__global__ void prep_wc(const float* __restrict__ Wo, const float* __restrict__ bo,
                        const float* __restrict__ Wvp, const float* __restrict__ bvp,
                        bf16_t* __restrict__ Wc, float* __restrict__ bcomb) {
  const int o = blockIdx.x;
  const int j = threadIdx.x;
  float a = 0.f;
#pragma unroll 8
  for (int i = 0; i < 512; ++i) a += Wo[o * 512 + i] * Wvp[i * 256 + j];
  Wc[o * 256 + j] = (bf16_t)a;
  if (j == 0) {
    float b = 0.f;
    for (int i = 0; i < 512; ++i) b += Wo[o * 512 + i] * bvp[i];
    bcomb[o] = b + bo[o];
  }
}

__global__ void prep_cast(const float* __restrict__ W1, const float* __restrict__ W2,
                          bf16_t* __restrict__ W1b, bf16_t* __restrict__ W2b) {
  const int idx = (blockIdx.x * 256 + threadIdx.x) * 8;
  const float* s;
  bf16_t* d;
  if (idx < 524288) { s = W1 + idx; d = W1b + idx; }
  else { s = W2 + (idx - 524288); d = W2b + (idx - 524288); }
  float4 u0 = *(const float4*)s;
  float4 u1 = *(const float4*)(s + 4);
  bf16x8 v;
  v[0] = (bf16_t)u0.x; v[1] = (bf16_t)u0.y; v[2] = (bf16_t)u0.z; v[3] = (bf16_t)u0.w;
  v[4] = (bf16_t)u1.x; v[5] = (bf16_t)u1.y; v[6] = (bf16_t)u1.z; v[7] = (bf16_t)u1.w;
  *(bf16x8*)d = v;
}

// ---------------- G1: 64x512 tile, K=256, LN1 fused (round-2 structure) ----------------
__global__ __launch_bounds__(256) void gemm_ln1(
    const float* __restrict__ Apf, const bf16_t* __restrict__ Bw,
    const float* __restrict__ bias, const float* __restrict__ cellRes,
    const float* __restrict__ gamma, const float* __restrict__ beta,
    bf16_t* __restrict__ outX) {
  __shared__ __align__(16) char smem[36864];   // lA 4KB @0, lB 32KB @4096; obuf overlays
  __shared__ float rs[4][64], rss[4][64];
  bf16_t (*lA)[32] = (bf16_t (*)[32])smem;
  bf16_t (*lB)[32] = (bf16_t (*)[32])(smem + 4096);

  const int t = threadIdx.x;
  const int lane = t & 63, w = t >> 6, r = lane & 15, q = lane >> 4;
  const int m0 = blockIdx.x * 64;

  f32x4 acc[4][8];
#pragma unroll
  for (int i = 0; i < 4; ++i)
#pragma unroll
    for (int j = 0; j < 8; ++j)
#pragma unroll
      for (int p = 0; p < 4; ++p) acc[i][j][p] = 0.f;

  const int arow = t >> 2, akc = (t & 3) * 8;

  for (int k0 = 0; k0 < 256; k0 += 32) {
#pragma unroll
    for (int jj = 0; jj < 8; ++jj) {
      const int c = t + 256 * jj;
      async_copy16(smem + 4096 + c * 16,
                   Bw + (size_t)(c >> 2) * 256 + k0 + (c & 3) * 8);
    }
    {
      const float* src = Apf + (size_t)(m0 + arow) * 256 + k0 + akc;
      float4 u0 = *(const float4*)src;
      float4 u1 = *(const float4*)(src + 4);
      bf16x8 v;
      v[0] = (bf16_t)u0.x; v[1] = (bf16_t)u0.y; v[2] = (bf16_t)u0.z; v[3] = (bf16_t)u0.w;
      v[4] = (bf16_t)u1.x; v[5] = (bf16_t)u1.y; v[6] = (bf16_t)u1.z; v[7] = (bf16_t)u1.w;
      *(bf16x8*)&lA[arow][akc] = v;
    }
    __syncthreads();
    bf16x8 af[4];
#pragma unroll
    for (int i = 0; i < 4; ++i) af[i] = *(const bf16x8*)&lA[16 * i + r][q * 8];
#pragma unroll
    for (int j = 0; j < 8; ++j) {
      bf16x8 bfv = *(const bf16x8*)&lB[128 * w + 16 * j + r][q * 8];
#pragma unroll
      for (int i = 0; i < 4; ++i)
        acc[i][j] = __builtin_amdgcn_mfma_f32_16x16x32_bf16(af[i], bfv, acc[i][j], 0, 0, 0);
    }
    __syncthreads();
  }

  float bb[8], ga[8], be[8];
#pragma unroll
  for (int j = 0; j < 8; ++j) {
    const int col = 128 * w + 16 * j + r;
    bb[j] = bias[col]; ga[j] = gamma[col]; be[j] = beta[col];
  }
  float s_[4][4], ss_[4][4];
#pragma unroll
  for (int i = 0; i < 4; ++i)
#pragma unroll
    for (int p = 0; p < 4; ++p) { s_[i][p] = 0.f; ss_[i][p] = 0.f; }
#pragma unroll
  for (int j = 0; j < 8; ++j) {
    const int col = 128 * w + 16 * j + r;
#pragma unroll
    for (int i = 0; i < 4; ++i)
#pragma unroll
      for (int p = 0; p < 4; ++p) {
        const int rowg = m0 + 16 * i + 4 * q + p;
        float v = acc[i][j][p] + bb[j] + cellRes[(size_t)rowg * 512 + col];
        acc[i][j][p] = v;
        s_[i][p] += v;
        ss_[i][p] += v * v;
      }
  }
#pragma unroll
  for (int m = 1; m <= 8; m <<= 1) {
#pragma unroll
    for (int i = 0; i < 4; ++i)
#pragma unroll
      for (int p = 0; p < 4; ++p) {
        s_[i][p] += __shfl_xor(s_[i][p], m);
        ss_[i][p] += __shfl_xor(ss_[i][p], m);
      }
  }
  if (r == 0) {
#pragma unroll
    for (int i = 0; i < 4; ++i)
#pragma unroll
      for (int p = 0; p < 4; ++p) {
        rs[w][16 * i + 4 * q + p] = s_[i][p];
        rss[w][16 * i + 4 * q + p] = ss_[i][p];
      }
  }
  __syncthreads();
  float mu[4][4], inv[4][4];
#pragma unroll
  for (int i = 0; i < 4; ++i)
#pragma unroll
    for (int p = 0; p < 4; ++p) {
      const int rl = 16 * i + 4 * q + p;
      float tS = rs[0][rl] + rs[1][rl] + rs[2][rl] + rs[3][rl];
      float tQ = rss[0][rl] + rss[1][rl] + rss[2][rl] + rss[3][rl];
      float m_ = tS * (1.0f / 512.0f);
      float v_ = tQ * (1.0f / 512.0f) - m_ * m_;
      mu[i][p] = m_;
      inv[i][p] = rsqrtf(v_ + 1e-5f);
    }
  bf16_t (*obuf)[520] = (bf16_t (*)[520])smem;
#pragma unroll
  for (int ph = 0; ph < 2; ++ph) {
#pragma unroll
    for (int i2 = 0; i2 < 2; ++i2) {
      const int i = ph * 2 + i2;
#pragma unroll
      for (int j = 0; j < 8; ++j)
#pragma unroll
        for (int p = 0; p < 4; ++p) {
          float v = (acc[i][j][p] - mu[i][p]) * inv[i][p] * ga[j] + be[j];
          obuf[16 * i2 + 4 * q + p][128 * w + 16 * j + r] = (bf16_t)v;
        }
    }
    __syncthreads();
    const int row = t >> 3, ch = t & 7;
#pragma unroll
    for (int cc = 0; cc < 8; ++cc) {
      bf16x8 v = *(const bf16x8*)&obuf[row][cc * 64 + ch * 8];
      *(bf16x8*)(outX + (size_t)(m0 + ph * 32 + row) * 512 + cc * 64 + ch * 8) = v;
    }
    __syncthreads();
  }
}

// ---------------- G2/G3: 128x128 tile, BK=64, XOR-swizzled LDS, n-fastest dispatch ----------------
// EPI 1: +bias, exact GELU -> bf16 out (ldo=1024), coalesced via LDS transpose. 8 n-blocks.
// EPI 2: +bias + bf16 residual -> fp32 out (ldo=512). 4 n-blocks.
template <int K, int EPI>
__global__ __launch_bounds__(256) void gemm128(
    const bf16_t* __restrict__ A, const bf16_t* __restrict__ Bw,
    const float* __restrict__ bias, const bf16_t* __restrict__ xRes,
    bf16_t* __restrict__ outBf, float* __restrict__ outF32, const int ldo) {
  __shared__ __align__(16) char smem[32768];  // lA 16KB @0, lB 16KB @16384; obuf overlays

  const int t = threadIdx.x;
  const int lane = t & 63, w = t >> 6, r = lane & 15, q = lane >> 4;
  constexpr int NBL = (EPI == 1) ? 3 : 2;
  // n-fastest swizzle: the 2^NBL blocks sharing an A-slab are adjacent in dispatch
  const int m0 = (blockIdx.x >> NBL) * 128;
  const int n0 = (blockIdx.x & ((1 << NBL) - 1)) * 128;
  const int rb = (w >> 1) * 64, cb = (w & 1) * 64;

  f32x4 acc[4][4];
#pragma unroll
  for (int i = 0; i < 4; ++i)
#pragma unroll
    for (int j = 0; j < 4; ++j)
#pragma unroll
      for (int p = 0; p < 4; ++p) acc[i][j][p] = 0.f;

  for (int k0 = 0; k0 < K; k0 += 64) {
    // stage 128x64 A and B; slot c holds (row = c>>3, src chunk = (c&7)^(row&7))
#pragma unroll
    for (int jj = 0; jj < 4; ++jj) {
      const int c = t + 256 * jj;
      const int row = c >> 3;
      const int sch = ((c & 7) ^ (row & 7)) * 8;
      async_copy16(smem + c * 16, A + (size_t)(m0 + row) * K + k0 + sch);
      async_copy16(smem + 16384 + c * 16, Bw + (size_t)(n0 + row) * K + k0 + sch);
    }
    __syncthreads();
#pragma unroll
    for (int kc2 = 0; kc2 < 2; ++kc2) {
      bf16x8 af[4], bfr[4];
#pragma unroll
      for (int i = 0; i < 4; ++i) {
        const int row = rb + 16 * i + r;
        const int ch = (kc2 * 4 + q) ^ (row & 7);
        af[i] = *(const bf16x8*)(smem + row * 128 + ch * 16);
      }
#pragma unroll
      for (int j = 0; j < 4; ++j) {
        const int row = cb + 16 * j + r;
        const int ch = (kc2 * 4 + q) ^ (row & 7);
        bfr[j] = *(const bf16x8*)(smem + 16384 + row * 128 + ch * 16);
      }
#pragma unroll
      for (int i = 0; i < 4; ++i)
#pragma unroll
        for (int j = 0; j < 4; ++j)
          acc[i][j] = __builtin_amdgcn_mfma_f32_16x16x32_bf16(af[i], bfr[j], acc[i][j], 0, 0, 0);
    }
    __syncthreads();
  }

  float bb[4];
#pragma unroll
  for (int j = 0; j < 4; ++j) bb[j] = bias[n0 + cb + 16 * j + r];

  if constexpr (EPI == 1) {
    bf16_t (*obuf)[136] = (bf16_t (*)[136])smem;  // 64*136*2 = 17408 <= 32768
#pragma unroll
    for (int ph = 0; ph < 2; ++ph) {
      if ((w >> 1) == ph) {
#pragma unroll
        for (int i = 0; i < 4; ++i)
#pragma unroll
          for (int j = 0; j < 4; ++j)
#pragma unroll
            for (int p = 0; p < 4; ++p) {
              float v = acc[i][j][p] + bb[j];
              float g = 0.5f * v * (1.0f + erff(v * 0.70710678118654752f));
              obuf[16 * i + 4 * q + p][cb + 16 * j + r] = (bf16_t)g;
            }
      }
      __syncthreads();
      const int row = t >> 2, ch = t & 3;
#pragma unroll
      for (int cc = 0; cc < 4; ++cc) {
        bf16x8 v = *(const bf16x8*)&obuf[row][cc * 32 + ch * 8];
        *(bf16x8*)(outBf + (size_t)(m0 + ph * 64 + row) * ldo + n0 + cc * 32 + ch * 8) = v;
      }
      __syncthreads();
    }
  } else {
#pragma unroll
    for (int i = 0; i < 4; ++i)
#pragma unroll
      for (int j = 0; j < 4; ++j)
#pragma unroll
        for (int p = 0; p < 4; ++p) {
          const int rowg = m0 + rb + 16 * i + 4 * q + p;
          const int col = n0 + cb + 16 * j + r;
          float v = acc[i][j][p] + bb[j] + (float)xRes[(size_t)rowg * 512 + col];
          outF32[(size_t)rowg * ldo + col] = v;
        }
  }
}

// ---------------- LN2: in-place row layernorm on d_out ----------------
__global__ __launch_bounds__(256) void ln2_kernel(float* __restrict__ y,
                                                  const float* __restrict__ g2,
                                                  const float* __restrict__ be2) {
  const int w = threadIdx.x >> 6, lane = threadIdx.x & 63;
  const size_t row = (size_t)blockIdx.x * 4 + w;
  float* p = y + row * 512 + lane * 8;
  float4 a = *(float4*)p;
  float4 b = *(float4*)(p + 4);
  float s = a.x + a.y + a.z + a.w + b.x + b.y + b.z + b.w;
  float ss = a.x * a.x + a.y * a.y + a.z * a.z + a.w * a.w +
             b.x * b.x + b.y * b.y + b.z * b.z + b.w * b.w;
#pragma unroll
  for (int m = 1; m <= 32; m <<= 1) {
    s += __shfl_xor(s, m);
    ss += __shfl_xor(ss, m);
  }
  const float mu = s * (1.0f / 512.0f);
  const float inv = rsqrtf(ss * (1.0f / 512.0f) - mu * mu + 1e-5f);
  const float4 ga0 = *(const float4*)(g2 + lane * 8);
  const float4 ga1 = *(const float4*)(g2 + lane * 8 + 4);
  const float4 be0 = *(const float4*)(be2 + lane * 8);
  const float4 be1 = *(const float4*)(be2 + lane * 8 + 4);
  a.x = (a.x - mu) * inv * ga0.x + be0.x;
  a.y = (a.y - mu) * inv * ga0.y + be0.y;
  a.z = (a.z - mu) * inv * ga0.z + be0.z;
  a.w = (a.w - mu) * inv * ga0.w + be0.w;
  b.x = (b.x - mu) * inv * ga1.x + be1.x;
  b.y = (b.y - mu) * inv * ga1.y + be1.y;
  b.z = (b.z - mu) * inv * ga1.z + be1.z;
  b.w = (b.w - mu) * inv * ga1.w + be1.w;
  *(float4*)p = a;
  *(float4*)(p + 4) = b;
}

extern "C" void kernel_launch(void* const* d_in, const int* in_sizes, int n_in,
                              void* d_out, int out_size, void* d_ws, size_t ws_size,
                              hipStream_t stream) {
  const float* cell = (const float*)d_in[0];
  const float* pert = (const float*)d_in[1];
  const float* Wp   = (const float*)d_in[2];
  const float* bp   = (const float*)d_in[3];
  // d_in[4..7] = Wq,bq,Wk,bk: dead (softmax over a single key == 1 -> attn = v)
  const float* Wv   = (const float*)d_in[8];
  const float* bv   = (const float*)d_in[9];
  const float* Wo   = (const float*)d_in[10];
  const float* bo   = (const float*)d_in[11];
  const float* g1   = (const float*)d_in[12];
  const float* be1  = (const float*)d_in[13];
  const float* g2   = (const float*)d_in[14];
  const float* be2  = (const float*)d_in[15];
  const float* W1   = (const float*)d_in[16];
  const float* b1   = (const float*)d_in[17];
  const float* W2   = (const float*)d_in[18];
  const float* b2   = (const float*)d_in[19];

  char* ws = (char*)d_ws;
  float*  Wvp   = (float*)(ws + 0);          // 524288
  float*  bvp   = (float*)(ws + 524288);     // 2048
  float*  bcomb = (float*)(ws + 526336);     // 2048
  bf16_t* Wc    = (bf16_t*)(ws + 528384);    // 262144
  bf16_t* W1b   = (bf16_t*)(ws + 790528);    // 1048576
  bf16_t* W2b   = (bf16_t*)(ws + 1839104);   // 1048576
  bf16_t* xws   = (bf16_t*)(ws + 2887680);   // 65536*512*2 = 67108864
  bf16_t* hws   = (bf16_t*)(ws + 69996544);  // 65536*1024*2 = 134217728
  (void)in_sizes; (void)n_in; (void)out_size; (void)ws_size;

  prep_wvp<<<512, 256, 0, stream>>>(Wv, Wp, bp, bv, Wvp, bvp);
  prep_wc<<<512, 256, 0, stream>>>(Wo, bo, Wvp, bvp, Wc, bcomb);
  prep_cast<<<512, 256, 0, stream>>>(W1, W2, W1b, W2b);

  // G1: x = LN1(cell + pert @ Wc.T + bcomb) -> bf16
  gemm_ln1<<<1024, 256, 0, stream>>>(pert, Wc, bcomb, cell, g1, be1, xws);
  // G2: h = gelu(x @ W1.T + b1) -> bf16 (512 m-blocks x 8 n-blocks, n fastest)
  gemm128<512, 1><<<4096, 256, 0, stream>>>(
      xws, W1b, b1, nullptr, hws, nullptr, 1024);
  // G3: y = x + h @ W2.T + b2 -> fp32 (512 m-blocks x 4 n-blocks, n fastest)
  gemm128<1024, 2><<<2048, 256, 0, stream>>>(
      hws, W2b, b2, xws, nullptr, (float*)d_out, 512);
  // LN2 in-place on d_out
  ln2_kernel<<<16384, 256, 0, stream>>>((float*)d_out, g2, be2);
}